// Round 2
// baseline (2091.372 us; speedup 1.0000x reference)
//
#include <hip/hip_runtime.h>

// SpeechVideoCrossAttention on MI355X (gfx950).  Round 2.
//
// Algebraic restructure (q_len == 1):
//   scores[b,h,k] = ln_v[b,k,:] . U[b,h,:] + q_h.bk_h,  U[b,h,:] = Wk[:,hslice] @ q_h
//   context[b,h,:] = pooled[b,h,:] @ Wv[:,hslice] + bv,  pooled = softmax-weighted ln_v
//
// R2 changes vs R1:
//   * attn2: scores via MFMA (A = vs in LDS, B = U direct-from-global with a
//     4-deep prefetch ring); vs row stride padded +8 shorts to break the
//     16-way LDS bank conflict of down-column b128 reads; video row loads
//     1-deep prefetched. Pooling stays VALU (MFMA form would need a
//     transposed vs copy = 128 KB LDS).
//   * u_gemm: 1024 blocks (64 Mtiles x 16 i-tiles) with the 16-head loop
//     INSIDE the block -> m97-density staging (64 K-iters/block) instead of
//     16384 shallow-K blocks.

#define B_TOT 8192
#define E     2048
#define NH    16
#define HD    128
#define KV    10
#define VSP   2056   // padded vs row stride in shorts (2048 + 8)

typedef short bf16x8 __attribute__((ext_vector_type(8)));
typedef float f32x4  __attribute__((ext_vector_type(4)));

__device__ __forceinline__ unsigned short f2bf(float f) {
  unsigned int u = __float_as_uint(f);
  u = (u + 0x7fffu + ((u >> 16) & 1u)) >> 16;   // round-to-nearest-even
  return (unsigned short)u;
}
__device__ __forceinline__ float bf2f(unsigned short h) {
  return __uint_as_float(((unsigned int)h) << 16);
}
__device__ __forceinline__ void unpack8(int4 v, float* f) {
  unsigned int x = (unsigned int)v.x, y = (unsigned int)v.y;
  unsigned int z = (unsigned int)v.z, w = (unsigned int)v.w;
  f[0] = __uint_as_float(x << 16); f[1] = __uint_as_float(x & 0xffff0000u);
  f[2] = __uint_as_float(y << 16); f[3] = __uint_as_float(y & 0xffff0000u);
  f[4] = __uint_as_float(z << 16); f[5] = __uint_as_float(z & 0xffff0000u);
  f[6] = __uint_as_float(w << 16); f[7] = __uint_as_float(w & 0xffff0000u);
}
__device__ __forceinline__ void async16(const void* g, void* l) {
  __builtin_amdgcn_global_load_lds(
      (const __attribute__((address_space(1))) unsigned int*)g,
      (__attribute__((address_space(3))) unsigned int*)l, 16, 0, 0);
}

// ---------------- LayerNorm of speech rows -> bf16 ----------------
__global__ __launch_bounds__(256) void ln_speech_kernel(
    const float* __restrict__ x, const float* __restrict__ g,
    const float* __restrict__ bb, unsigned short* __restrict__ out)
{
  __shared__ float red[8];
  const int tid = threadIdx.x, wave = tid >> 6, lane = tid & 63;
  const long b = blockIdx.x;
  const float4* row = (const float4*)(x + b * E);
  float4 a0 = row[tid], a1 = row[tid + 256];
  float s  = a0.x + a0.y + a0.z + a0.w + a1.x + a1.y + a1.z + a1.w;
  float s2 = a0.x*a0.x + a0.y*a0.y + a0.z*a0.z + a0.w*a0.w
           + a1.x*a1.x + a1.y*a1.y + a1.z*a1.z + a1.w*a1.w;
  #pragma unroll
  for (int off = 32; off; off >>= 1) { s += __shfl_xor(s, off); s2 += __shfl_xor(s2, off); }
  if (lane == 0) { red[wave] = s; red[wave + 4] = s2; }
  __syncthreads();
  s  = red[0] + red[1] + red[2] + red[3];
  s2 = red[4] + red[5] + red[6] + red[7];
  const float mu = s * (1.0f / E);
  const float rs = rsqrtf(s2 * (1.0f / E) - mu * mu + 1e-5f);
  const float4* g4 = (const float4*)g;
  const float4* b4 = (const float4*)bb;
  ushort4* o = (ushort4*)(out + b * E);
  {
    float4 gg = g4[tid], bv = b4[tid];
    ushort4 r;
    r.x = f2bf((a0.x - mu) * rs * gg.x + bv.x);
    r.y = f2bf((a0.y - mu) * rs * gg.y + bv.y);
    r.z = f2bf((a0.z - mu) * rs * gg.z + bv.z);
    r.w = f2bf((a0.w - mu) * rs * gg.w + bv.w);
    o[tid] = r;
  }
  {
    float4 gg = g4[tid + 256], bv = b4[tid + 256];
    ushort4 r;
    r.x = f2bf((a1.x - mu) * rs * gg.x + bv.x);
    r.y = f2bf((a1.y - mu) * rs * gg.y + bv.y);
    r.z = f2bf((a1.z - mu) * rs * gg.z + bv.z);
    r.w = f2bf((a1.w - mu) * rs * gg.w + bv.w);
    o[tid + 256] = r;
  }
}

// ---------------- transpose + cast fp32 -> bf16 (Wq, Wv, Wo) ----------------
__global__ __launch_bounds__(256) void wtrans_kernel(
    const float* __restrict__ Wq, const float* __restrict__ Wv, const float* __restrict__ Wo,
    unsigned short* __restrict__ WqT, unsigned short* __restrict__ WvT, unsigned short* __restrict__ WoT)
{
  __shared__ float t[32][33];
  const float* W; unsigned short* WT;
  if (blockIdx.z == 0)      { W = Wq; WT = WqT; }
  else if (blockIdx.z == 1) { W = Wv; WT = WvT; }
  else                      { W = Wo; WT = WoT; }
  const int tx = threadIdx.x, ty = threadIdx.y;
  const int n0 = blockIdx.x * 32, k0 = blockIdx.y * 32;
  #pragma unroll
  for (int j = 0; j < 4; j++)
    t[ty + 8*j][tx] = W[(long)(k0 + ty + 8*j) * E + n0 + tx];
  __syncthreads();
  #pragma unroll
  for (int j = 0; j < 4; j++)
    WT[(long)(n0 + ty + 8*j) * E + k0 + tx] = f2bf(t[tx][ty + 8*j]);
}

// ---------------- plain cast fp32 -> bf16 (Wk keeps [in][out] layout) --------
__global__ __launch_bounds__(256) void wcast_kernel(
    const float* __restrict__ W, unsigned short* __restrict__ Wb)
{
  const long i = ((long)blockIdx.x * 256 + threadIdx.x) * 4;
  float4 v = *(const float4*)(W + i);
  ushort4 o;
  o.x = f2bf(v.x); o.y = f2bf(v.y); o.z = f2bf(v.z); o.w = f2bf(v.w);
  *(ushort4*)(Wb + i) = o;
}

// ---------------- m97-style bf16 GEMM, B^T input, 128x128 tile, BK=32 --------
// C[m,n] = sum_k A[m,k] * BT[n,k]  (+ bias[n]); z-batched via strides.
template<bool OUT_BF16, bool HAS_BIAS>
__global__ __launch_bounds__(256) void gemm_bt_kernel(
    const unsigned short* __restrict__ A, int lda, long sAz,
    const unsigned short* __restrict__ BT, int ldb, long sBz,
    void* __restrict__ Cv, int ldc, long sCz,
    const float* __restrict__ bias, int sBiasz, int Ksize)
{
  __shared__ unsigned short As[128 * 32];
  __shared__ unsigned short Bs[128 * 32];
  const int tid = threadIdx.x, wave = tid >> 6, lane = tid & 63;
  A  += (long)blockIdx.z * sAz;
  BT += (long)blockIdx.z * sBz;
  const int tileM = blockIdx.x * 128, tileN = blockIdx.y * 128;
  const int r0 = wave * 16 + (lane >> 2);
  const int cb = (lane & 3) * 8;
  const unsigned short* Ag0 = A  + (long)(tileM + r0) * lda + cb;
  const unsigned short* Ag1 = A  + (long)(tileM + r0 + 64) * lda + cb;
  const unsigned short* Bg0 = BT + (long)(tileN + r0) * ldb + cb;
  const unsigned short* Bg1 = BT + (long)(tileN + r0 + 64) * ldb + cb;
  unsigned short* As0 = As + wave * 512;
  unsigned short* As1 = As + (wave + 4) * 512;
  unsigned short* Bs0 = Bs + wave * 512;
  unsigned short* Bs1 = Bs + (wave + 4) * 512;
  const int wm = wave & 1, wn = wave >> 1;
  const int quad = lane >> 4, l15 = lane & 15;
  const unsigned short* Ard = As + (wm * 64 + l15) * 32 + quad * 8;
  const unsigned short* Brd = Bs + (wn * 64 + l15) * 32 + quad * 8;

  f32x4 acc[4][4] = {};

  for (int k0 = 0; k0 < Ksize; k0 += 32) {
    __syncthreads();
    async16(Ag0 + k0, As0);
    async16(Ag1 + k0, As1);
    async16(Bg0 + k0, Bs0);
    async16(Bg1 + k0, Bs1);
    __syncthreads();
    bf16x8 af[4], bfv[4];
    #pragma unroll
    for (int im = 0; im < 4; im++) af[im]  = *(const bf16x8*)(Ard + im * 512);
    #pragma unroll
    for (int in = 0; in < 4; in++) bfv[in] = *(const bf16x8*)(Brd + in * 512);
    #pragma unroll
    for (int im = 0; im < 4; im++)
      #pragma unroll
      for (int in = 0; in < 4; in++)
        acc[im][in] = __builtin_amdgcn_mfma_f32_16x16x32_bf16(af[im], bfv[in], acc[im][in], 0, 0, 0);
  }

  const long czoff = (long)blockIdx.z * sCz;
  #pragma unroll
  for (int in = 0; in < 4; in++) {
    const int gn = tileN + wn * 64 + in * 16 + l15;
    const float badd = HAS_BIAS ? bias[(long)blockIdx.z * sBiasz + gn] : 0.0f;
    #pragma unroll
    for (int im = 0; im < 4; im++) {
      const int gm = tileM + wm * 64 + im * 16 + quad * 4;
      #pragma unroll
      for (int r = 0; r < 4; r++) {
        const float v = acc[im][in][r] + badd;
        const long off = czoff + (long)(gm + r) * ldc + gn;
        if (OUT_BF16) ((unsigned short*)Cv)[off] = f2bf(v);
        else          ((float*)Cv)[off] = v;
      }
    }
  }
}

// ---------------- U-GEMM: head loop INSIDE the block --------------------
// U[b,h,i] = sum_{k<128} Qb[b, h*128+k] * Wk[i, h*128+k]
// grid (Mtiles=rows/128, 16 i-tiles); per block: 16 heads x 4 staging iters.
__global__ __launch_bounds__(256) void u_gemm_kernel(
    const unsigned short* __restrict__ Qb,   // [rows, 2048] (chunk base applied)
    const unsigned short* __restrict__ Wkb,  // [2048, 2048]
    unsigned short* __restrict__ U)          // [rows, 16, 2048] chunk-local
{
  __shared__ unsigned short As[128 * 32];
  __shared__ unsigned short Bs[128 * 32];
  const int tid = threadIdx.x, wave = tid >> 6, lane = tid & 63;
  const int tileM = blockIdx.x * 128, tileN = blockIdx.y * 128;
  const int r0 = wave * 16 + (lane >> 2);
  const int cb = (lane & 3) * 8;
  const unsigned short* Ag0 = Qb  + (long)(tileM + r0) * E + cb;
  const unsigned short* Ag1 = Qb  + (long)(tileM + r0 + 64) * E + cb;
  const unsigned short* Bg0 = Wkb + (long)(tileN + r0) * E + cb;
  const unsigned short* Bg1 = Wkb + (long)(tileN + r0 + 64) * E + cb;
  unsigned short* As0 = As + wave * 512;
  unsigned short* As1 = As + (wave + 4) * 512;
  unsigned short* Bs0 = Bs + wave * 512;
  unsigned short* Bs1 = Bs + (wave + 4) * 512;
  const int wm = wave & 1, wn = wave >> 1;
  const int quad = lane >> 4, l15 = lane & 15;
  const unsigned short* Ard = As + (wm * 64 + l15) * 32 + quad * 8;
  const unsigned short* Brd = Bs + (wn * 64 + l15) * 32 + quad * 8;

  for (int h = 0; h < NH; h++) {
    f32x4 acc[4][4] = {};
    const int hoff = h * HD;
    #pragma unroll
    for (int k0 = 0; k0 < HD; k0 += 32) {
      __syncthreads();
      async16(Ag0 + hoff + k0, As0);
      async16(Ag1 + hoff + k0, As1);
      async16(Bg0 + hoff + k0, Bs0);
      async16(Bg1 + hoff + k0, Bs1);
      __syncthreads();
      bf16x8 af[4], bfv[4];
      #pragma unroll
      for (int im = 0; im < 4; im++) af[im]  = *(const bf16x8*)(Ard + im * 512);
      #pragma unroll
      for (int in = 0; in < 4; in++) bfv[in] = *(const bf16x8*)(Brd + in * 512);
      #pragma unroll
      for (int im = 0; im < 4; im++)
        #pragma unroll
        for (int in = 0; in < 4; in++)
          acc[im][in] = __builtin_amdgcn_mfma_f32_16x16x32_bf16(af[im], bfv[in], acc[im][in], 0, 0, 0);
    }
    #pragma unroll
    for (int in = 0; in < 4; in++) {
      const int gn = tileN + wn * 64 + in * 16 + l15;            // i
      #pragma unroll
      for (int im = 0; im < 4; im++) {
        const int gm = tileM + wm * 64 + im * 16 + quad * 4;     // b
        #pragma unroll
        for (int r = 0; r < 4; r++)
          U[((long)(gm + r) * NH + h) * E + gn] = f2bf(acc[im][in][r]);
      }
    }
  }
}

// ---------------- attn2: LN(video)->LDS, MFMA scores, softmax, VALU pool -----
// One block per batch row. vs[16][VSP] bf16 (rows 10..15 zero), 64 KB-ish.
// scores D[m=k][n=h] = sum_i vs[k,i] * U[b,h,i]:
//   A-frag  lane: vs[l15][i0+quad*8 ..+8]      (ds_read_b128, pad kills conflicts)
//   B-frag  lane: U[b, l15, i0+quad*8 ..+8]    (global dwordx4, 4-deep prefetch)
// Pooling overwrites U[b,h,:] in place (barrier-separated from score reads).
__global__ __launch_bounds__(256) void attn2_kernel(
    const float* __restrict__ video, const float* __restrict__ lvg,
    const float* __restrict__ lvb,
    const unsigned short* __restrict__ Qb, const float* __restrict__ bk,
    unsigned short* U, float* __restrict__ probs,
    const float* __restrict__ alphap, int b_base)
{
  __shared__ unsigned short vs[16 * VSP];   // 65792 B
  __shared__ float sred[4 * 256];           // 4 KB
  __shared__ float p_lds[16 * 16];          // 1 KB
  __shared__ float qdb_lds[16];
  const int tid = threadIdx.x, wave = tid >> 6, lane = tid & 63;
  const int quad = lane >> 4, l15 = lane & 15;
  const int bl = blockIdx.x;
  const long b = (long)b_base + bl;
  const unsigned short* Ub = U + (long)bl * NH * E;

  // ---- Phase 1: video prefetch + U prefetch + zero pad rows + LN + qdb ----
  const int kcount = (wave < 2) ? 3 : 2;
  float4 xv[2][8];
  {
    const float4* row = (const float4*)(video + (b * KV + wave) * E);
    #pragma unroll
    for (int it = 0; it < 8; it++) xv[0][it] = row[lane + it * 64];
  }
  // U B-frag prefetch ring (chunks of 32 i per wave's 512-i slice)
  const unsigned short* Uw = Ub + (long)l15 * E + wave * 512 + quad * 8;
  int4 bfrag[4];
  #pragma unroll
  for (int c = 0; c < 4; c++) bfrag[c] = *(const int4*)(Uw + c * 32);

  // zero rows 10..15 (6 * VSP shorts = 1542 int4, 16B-aligned region)
  {
    int4 z; z.x = 0; z.y = 0; z.z = 0; z.w = 0;
    int4* dst = (int4*)(vs + 10 * VSP);
    for (int i = tid; i < 6 * VSP / 8; i += 256) dst[i] = z;
  }

  for (int r = 0; r < kcount; r++) {
    const int k = wave + r * 4;
    if (r + 1 < kcount) {
      const float4* nrow = (const float4*)(video + (b * KV + wave + (r + 1) * 4) * E);
      #pragma unroll
      for (int it = 0; it < 8; it++) xv[(r + 1) & 1][it] = nrow[lane + it * 64];
    }
    float4* xr = xv[r & 1];
    float s = 0.f, s2 = 0.f;
    #pragma unroll
    for (int it = 0; it < 8; it++) {
      s  += xr[it].x + xr[it].y + xr[it].z + xr[it].w;
      s2 += xr[it].x*xr[it].x + xr[it].y*xr[it].y + xr[it].z*xr[it].z + xr[it].w*xr[it].w;
    }
    #pragma unroll
    for (int off = 32; off; off >>= 1) { s += __shfl_xor(s, off); s2 += __shfl_xor(s2, off); }
    const float mu = s * (1.0f / E);
    const float rs = rsqrtf(s2 * (1.0f / E) - mu * mu + 1e-5f);
    #pragma unroll
    for (int it = 0; it < 8; it++) {
      const int i4 = lane + it * 64;
      float4 gg = ((const float4*)lvg)[i4];
      float4 bb = ((const float4*)lvb)[i4];
      ushort4 o;
      o.x = f2bf((xr[it].x - mu) * rs * gg.x + bb.x);
      o.y = f2bf((xr[it].y - mu) * rs * gg.y + bb.y);
      o.z = f2bf((xr[it].z - mu) * rs * gg.z + bb.z);
      o.w = f2bf((xr[it].w - mu) * rs * gg.w + bb.w);
      ((ushort4*)&vs[k * VSP])[i4] = o;
    }
  }
  // qdb[h] = q_h . bk_h  (exact softmax shift)
  #pragma unroll
  for (int hh = 0; hh < 4; hh++) {
    const int h = wave + hh * 4;
    const float q0 = bf2f(Qb[b * E + h * HD + lane]);
    const float q1 = bf2f(Qb[b * E + h * HD + 64 + lane]);
    float qd = q0 * bk[h * HD + lane] + q1 * bk[h * HD + 64 + lane];
    #pragma unroll
    for (int off = 32; off; off >>= 1) qd += __shfl_xor(qd, off);
    if (lane == 0) qdb_lds[h] = qd;
  }
  __syncthreads();

  // ---- Phase 2: MFMA scores over this wave's 512-i slice ----
  const unsigned short* vsrd = vs + l15 * VSP + wave * 512 + quad * 8;
  f32x4 sacc = {};
  #pragma unroll
  for (int j = 0; j < 16; j++) {
    bf16x8 af = *(const bf16x8*)(vsrd + j * 32);
    bf16x8 bf = *(const bf16x8*)&bfrag[j & 3];
    sacc = __builtin_amdgcn_mfma_f32_16x16x32_bf16(af, bf, sacc, 0, 0, 0);
    if (j + 4 < 16) bfrag[j & 3] = *(const int4*)(Uw + (j + 4) * 32);
  }
  #pragma unroll
  for (int r = 0; r < 4; r++)
    sred[wave * 256 + (quad * 4 + r) * 16 + l15] = sacc[r];
  __syncthreads();

  // ---- Phase 3: cross-wave combine ----
  {
    const float sc = sred[tid] + sred[256 + tid] + sred[512 + tid] + sred[768 + tid];
    __syncthreads();
    sred[tid] = sc;
  }
  __syncthreads();

  // ---- Phase 4: softmax by 16 threads (h = tid) ----
  if (tid < NH) {
    const int h = tid;
    const float alpha = alphap[0];
    const float rsd = 0.088388347648318447f;  // 1/sqrt(128)
    const float qd = qdb_lds[h];
    float sv[KV];
    float mx = -1e30f;
    #pragma unroll
    for (int k = 0; k < KV; k++) {
      float s = (sred[k * 16 + h] + qd) * rsd;
      s = fminf(fmaxf(s, -1000.f), 1000.f);
      s += fmaxf(-alpha * (float)(k * k), -10.f);
      sv[k] = s;
      mx = fmaxf(mx, s);
    }
    float sum = 0.f;
    #pragma unroll
    for (int k = 0; k < KV; k++) { sv[k] = __expf(sv[k] - mx); sum += sv[k]; }
    const float inv = 1.0f / sum;
    #pragma unroll
    for (int k = 0; k < KV; k++) {
      const float pv = sv[k] * inv;
      p_lds[h * 16 + k] = pv;
      probs[(b * NH + h) * KV + k] = pv;
    }
  }
  __syncthreads();

  // ---- Phase 5: pooling (VALU), overwrite U[b,h,:] ----
  float pk[4][KV];
  #pragma unroll
  for (int hh = 0; hh < 4; hh++) {
    const int h = wave + hh * 4;
    #pragma unroll
    for (int k = 0; k < KV; k++) pk[hh][k] = p_lds[h * 16 + k];
  }
  for (int it = 0; it < 4; it++) {
    const int i0 = lane * 8 + it * 512;
    float pv[4][8];
    #pragma unroll
    for (int hh = 0; hh < 4; hh++)
      #pragma unroll
      for (int j = 0; j < 8; j++) pv[hh][j] = 0.f;
    #pragma unroll
    for (int k = 0; k < KV; k++) {
      int4 vvp = *(const int4*)&vs[k * VSP + i0];
      float vf[8]; unpack8(vvp, vf);
      #pragma unroll
      for (int hh = 0; hh < 4; hh++)
        #pragma unroll
        for (int j = 0; j < 8; j++)
          pv[hh][j] += pk[hh][k] * vf[j];
    }
    #pragma unroll
    for (int hh = 0; hh < 4; hh++) {
      const int h = wave + hh * 4;
      unsigned int w0 = (unsigned int)f2bf(pv[hh][0]) | ((unsigned int)f2bf(pv[hh][1]) << 16);
      unsigned int w1 = (unsigned int)f2bf(pv[hh][2]) | ((unsigned int)f2bf(pv[hh][3]) << 16);
      unsigned int w2 = (unsigned int)f2bf(pv[hh][4]) | ((unsigned int)f2bf(pv[hh][5]) << 16);
      unsigned int w3 = (unsigned int)f2bf(pv[hh][6]) | ((unsigned int)f2bf(pv[hh][7]) << 16);
      int4 st; st.x = (int)w0; st.y = (int)w1; st.z = (int)w2; st.w = (int)w3;
      *(int4*)(U + ((long)bl * NH + h) * E + i0) = st;
    }
  }
}

extern "C" void kernel_launch(void* const* d_in, const int* in_sizes, int n_in,
                              void* d_out, int out_size, void* d_ws, size_t ws_size,
                              hipStream_t stream) {
  const float* speech = (const float*)d_in[0];
  const float* video  = (const float*)d_in[1];
  const float* ln_s_g = (const float*)d_in[2];
  const float* ln_s_b = (const float*)d_in[3];
  const float* ln_v_g = (const float*)d_in[4];
  const float* ln_v_b = (const float*)d_in[5];
  const float* Wq = (const float*)d_in[6];
  const float* bq = (const float*)d_in[7];
  const float* Wk = (const float*)d_in[8];
  const float* bk = (const float*)d_in[9];
  const float* Wv = (const float*)d_in[10];
  const float* bv = (const float*)d_in[11];
  const float* Wo = (const float*)d_in[12];
  const float* bo = (const float*)d_in[13];
  const float* alphap = (const float*)d_in[14];

  char* ws = (char*)d_ws;
  unsigned short* sN  = (unsigned short*)(ws);               // 33,554,432 B
  unsigned short* Qb  = (unsigned short*)(ws + 33554432);    // 33,554,432 B
  unsigned short* ctx = (unsigned short*)(ws + 67108864);    // 33,554,432 B
  unsigned short* WqT = (unsigned short*)(ws + 100663296);   //  8,388,608 B
  unsigned short* WvT = (unsigned short*)(ws + 109051904);   //  8,388,608 B
  unsigned short* WoT = (unsigned short*)(ws + 117440512);   //  8,388,608 B
  unsigned short* Wkb = (unsigned short*)(ws + 125829120);   //  8,388,608 B
  unsigned short* U   = (unsigned short*)(ws + 134217728);   // up to 536,870,912 B

  float* out0  = (float*)d_out;
  float* probs = out0 + (long)B_TOT * E;   // attn_probs [B,16,10]

  const size_t fixed = 134217728;
  long rows_cap = 0;
  if (ws_size > fixed) rows_cap = (long)((ws_size - fixed) / ((size_t)NH * E * 2));
  int chunk = (int)((rows_cap / 128) * 128);
  if (chunk > B_TOT) chunk = B_TOT;
  if (chunk < 128)   chunk = 128;

  ln_speech_kernel<<<B_TOT, 256, 0, stream>>>(speech, ln_s_g, ln_s_b, sN);
  wtrans_kernel<<<dim3(64, 64, 3), dim3(32, 8), 0, stream>>>(Wq, Wv, Wo, WqT, WvT, WoT);
  wcast_kernel<<<4096, 256, 0, stream>>>(Wk, Wkb);

  // Q = sN @ Wq + bq
  gemm_bt_kernel<true, true><<<dim3(64, 16, 1), 256, 0, stream>>>(
      sN, E, 0, WqT, E, 0, Qb, E, 0, bq, 0, E);

  for (int b0 = 0; b0 < B_TOT; b0 += chunk) {
    const int rows = (B_TOT - b0 < chunk) ? (B_TOT - b0) : chunk;
    // U[b,h,i] (head loop inside block)
    u_gemm_kernel<<<dim3(rows / 128, 16), 256, 0, stream>>>(
        Qb + (long)b0 * E, Wkb, U);
    // fused LN(video) + MFMA scores + softmax + pool (U -> pooled in place)
    attn2_kernel<<<rows, 256, 0, stream>>>(video, ln_v_g, ln_v_b, Qb, bk, U, probs, alphap, b0);
    // ctx[b, hslice] = pooled[b,h,:] @ Wv[:, hslice] + bv
    gemm_bt_kernel<true, true><<<dim3(rows / 128, 1, NH), 256, 0, stream>>>(
        U, NH * E, E, WvT, E, (long)HD * E, ctx + (long)b0 * E, E, HD, bv, HD, E);
  }

  // out = ctx @ Wo + bo  (fp32)
  gemm_bt_kernel<false, true><<<dim3(64, 16, 1), 256, 0, stream>>>(
      ctx, E, 0, WoT, E, 0, out0, E, 0, bo, 0, E);
}